// Round 8
// baseline (298.514 us; speedup 1.0000x reference)
//
#include <hip/hip_runtime.h>
#include <hip/hip_fp16.h>
#include <cmath>

#define D 64
#define PA_EDGES 4096     // edges per partition/bhist block
#define BSHIFT 7          // bucket = 128 nodes
#define BNODES 128
#define MAXBUCK 1024      // supports N <= 131072
#define PB_CAP 4096       // LDS csr staging per bucket (avg 2048, ~45 sigma)

// ---------------------------------------------------------------------------
// Per-BUCKET histogram, LDS-privatized. Each block pre-aggregates 4096 edges
// in LDS, flushes <=nbuck aggregated atomics (replaces 1.6M random atomics).
// ---------------------------------------------------------------------------
__global__ __launch_bounds__(256)
void bhist_kernel(const int* __restrict__ dst, int* __restrict__ bcnt, int E, int nbuck) {
    __shared__ int lh[MAXBUCK];
    const int t = threadIdx.x;
    const int e0 = blockIdx.x * PA_EDGES;
    const int ecnt = min(PA_EDGES, E - e0);
    for (int i = t; i < MAXBUCK; i += 256) lh[i] = 0;
    __syncthreads();
    for (int i = t; i < ecnt; i += 256) atomicAdd(&lh[dst[e0 + i] >> BSHIFT], 1);
    __syncthreads();
    for (int b = t; b < nbuck; b += 256) {
        const int c = lh[b];
        if (c) atomicAdd(&bcnt[b], c);
    }
}

// ---------------------------------------------------------------------------
// Exclusive scan of bucket counts -> bbase (and cursor copy). One block.
// ---------------------------------------------------------------------------
__global__ __launch_bounds__(256)
void bucket_scan_kernel(const int* __restrict__ bcnt, int* __restrict__ bbase,
                        int* __restrict__ cursor, int nbuck, int E) {
    __shared__ int red[256];
    const int t = threadIdx.x;
    const int c0 = (4 * t + 0 < nbuck) ? bcnt[4 * t + 0] : 0;
    const int c1 = (4 * t + 1 < nbuck) ? bcnt[4 * t + 1] : 0;
    const int c2 = (4 * t + 2 < nbuck) ? bcnt[4 * t + 2] : 0;
    const int c3 = (4 * t + 3 < nbuck) ? bcnt[4 * t + 3] : 0;
    red[t] = c0 + c1 + c2 + c3;
    __syncthreads();
    for (int off = 1; off < 256; off <<= 1) {
        int u = (t >= off) ? red[t - off] : 0;
        __syncthreads();
        red[t] += u;
        __syncthreads();
    }
    const int excl = (t == 0) ? 0 : red[t - 1];
    const int e0 = excl, e1 = excl + c0, e2 = excl + c0 + c1, e3 = excl + c0 + c1 + c2;
    if (4 * t + 0 <= nbuck) { bbase[4 * t + 0] = e0; }
    if (4 * t + 1 <= nbuck) { bbase[4 * t + 1] = e1; }
    if (4 * t + 2 <= nbuck) { bbase[4 * t + 2] = e2; }
    if (4 * t + 3 <= nbuck) { bbase[4 * t + 3] = e3; }
    if (4 * t + 0 < nbuck) cursor[4 * t + 0] = e0;
    if (4 * t + 1 < nbuck) cursor[4 * t + 1] = e1;
    if (4 * t + 2 < nbuck) cursor[4 * t + 2] = e2;
    if (4 * t + 3 < nbuck) cursor[4 * t + 3] = e3;
    if (t == 255) bbase[nbuck] = E;   // total (exclusive scan end)
}

// ---------------------------------------------------------------------------
// Bucket partition: (src, dst) -> packed 32-bit (src<<7 | dst&127), grouped
// by bucket (dst>>7) in `pairs`. LDS-staged; int LDS atomics only (native
// ds_add_u32 -- float LDS atomics are CAS loops on HIP, never use them).
// ---------------------------------------------------------------------------
__global__ __launch_bounds__(256)
void partition_kernel(const int* __restrict__ src, const int* __restrict__ dst,
                      int* __restrict__ cursor, unsigned* __restrict__ pairs,
                      int E, int nbuck) {
    __shared__ int lhist[MAXBUCK];            // counts, then local fill cursors
    __shared__ int lbase[MAXBUCK];            // local exclusive scan
    __shared__ int gbase[MAXBUCK];            // reserved global positions
    __shared__ int red[256];
    __shared__ unsigned stage[PA_EDGES];      // 16 KB
    __shared__ unsigned short sbuck[PA_EDGES];// 8 KB bucket id per staged slot

    const int t = threadIdx.x;
    const int e0 = blockIdx.x * PA_EDGES;
    const int ecnt = min(PA_EDGES, E - e0);

    for (int i = t; i < MAXBUCK; i += 256) lhist[i] = 0;
    __syncthreads();
    for (int i = t; i < ecnt; i += 256) atomicAdd(&lhist[dst[e0 + i] >> BSHIFT], 1);
    __syncthreads();

    // exclusive scan over 1024 entries: each thread owns 4 consecutive slots
    const int c0 = lhist[4 * t], c1 = lhist[4 * t + 1];
    const int c2 = lhist[4 * t + 2], c3 = lhist[4 * t + 3];
    red[t] = c0 + c1 + c2 + c3;
    __syncthreads();
    for (int off = 1; off < 256; off <<= 1) {
        int u = (t >= off) ? red[t - off] : 0;
        __syncthreads();
        red[t] += u;
        __syncthreads();
    }
    const int excl = (t == 0) ? 0 : red[t - 1];
    lbase[4 * t]     = excl;
    lbase[4 * t + 1] = excl + c0;
    lbase[4 * t + 2] = excl + c0 + c1;
    lbase[4 * t + 3] = excl + c0 + c1 + c2;
    for (int b = t; b < nbuck; b += 256) {
        const int c = lhist[b];
        gbase[b] = c ? atomicAdd(&cursor[b], c) : 0;
    }
    __syncthreads();
    for (int i = t; i < MAXBUCK; i += 256) lhist[i] = 0;   // reuse as fill cursors
    __syncthreads();
    for (int i = t; i < ecnt; i += 256) {
        const int d = dst[e0 + i];
        const int b = d >> BSHIFT;
        const int p = lbase[b] + atomicAdd(&lhist[b], 1);
        stage[p] = ((unsigned)src[e0 + i] << BSHIFT) | (unsigned)(d & (BNODES - 1));
        sbuck[p] = (unsigned short)b;
    }
    __syncthreads();
    for (int i = t; i < ecnt; i += 256) {
        const int b = sbuck[i];
        pairs[gbase[b] + (i - lbase[b])] = stage[i];
    }
}

// ---------------------------------------------------------------------------
// Bucket CSR fill + per-node rowStart derivation, fully on-chip.
// ---------------------------------------------------------------------------
__global__ __launch_bounds__(256)
void bucket_fill_kernel(const unsigned* __restrict__ pairs, const int* __restrict__ bbase,
                        int* __restrict__ rowStart, int* __restrict__ csr, int n, int E) {
    __shared__ int lcsr[PB_CAP];          // 16 KB
    __shared__ int lcnt[BNODES];          // per-node degree
    __shared__ int lrs[BNODES];           // per-node row start (bucket-relative)
    __shared__ int s[BNODES];             // scan workspace
    __shared__ int lfill[BNODES];
    const int t = threadIdx.x;
    const int node0 = blockIdx.x << BSHIFT;
    const int bn = min(BNODES, n - node0);
    const int base = bbase[blockIdx.x];
    const int cntE = bbase[blockIdx.x + 1] - base;

    if (t < BNODES) { lcnt[t] = 0; lfill[t] = 0; }
    __syncthreads();
    for (int i = t; i < cntE; i += 256)
        atomicAdd(&lcnt[pairs[base + i] & (BNODES - 1)], 1);
    __syncthreads();
    if (t < BNODES) s[t] = lcnt[t];
    __syncthreads();
    for (int off = 1; off < BNODES; off <<= 1) {
        int u = (t >= off && t < BNODES) ? s[t - off] : 0;
        __syncthreads();
        if (t < BNODES) s[t] += u;
        __syncthreads();
    }
    if (t < BNODES) lrs[t] = (t == 0) ? 0 : s[t - 1];
    __syncthreads();
    if (t < bn) rowStart[node0 + t] = base + lrs[t];
    if (blockIdx.x == gridDim.x - 1 && t == 0) rowStart[n] = E;

    if (cntE <= PB_CAP) {
        for (int i = t; i < cntE; i += 256) {
            const unsigned pr = pairs[base + i];
            const int dl = (int)(pr & (BNODES - 1));
            const int p = lrs[dl] + atomicAdd(&lfill[dl], 1);
            lcsr[p] = (int)(pr >> BSHIFT);
        }
        __syncthreads();
        for (int i = t; i < cntE; i += 256) csr[base + i] = lcsr[i];
    } else {   // safety fallback (statistically unreachable for random dst)
        for (int i = t; i < cntE; i += 256) {
            const unsigned pr = pairs[base + i];
            const int dl = (int)(pr & (BNODES - 1));
            const int p = base + lrs[dl] + atomicAdd(&lfill[dl], 1);
            csr[p] = (int)(pr >> BSHIFT);
        }
    }
}

// ---------------------------------------------------------------------------
// f32 -> f16 cast (vectorized, grid-stride).
// ---------------------------------------------------------------------------
__global__ __launch_bounds__(256)
void cast_half_kernel(const float* __restrict__ in, __half* __restrict__ out, int n2) {
    const float2* in2 = (const float2*)in;
    __half2* out2 = (__half2*)out;
    int i = blockIdx.x * 256 + threadIdx.x;
    const int st = gridDim.x * 256;
    for (; i < n2; i += st) {
        const float2 v = in2[i];
        out2[i] = __floats2half2_rn(v.x, v.y);
    }
}

// ---------------------------------------------------------------------------
// Gather-mean from an fp16 feature copy: m[node] = mean(xh[nbrs(node)]).
// One wave per node; lane-group g (16 lanes) loads one neighbor row (128 B)
// via 8 B dwordx2 -> 4 rows in flight per gather batch. f32 accumulation.
// ---------------------------------------------------------------------------
__device__ __forceinline__ void addh4(float4& a, const __half* __restrict__ p) {
    union { unsigned long long u; __half2 h[2]; } r;
    r.u = *(const unsigned long long*)p;       // 8 B load
    const float2 f0 = __half22float2(r.h[0]);
    const float2 f1 = __half22float2(r.h[1]);
    a.x += f0.x; a.y += f0.y; a.z += f1.x; a.w += f1.y;
}

__global__ __launch_bounds__(256)
void aggmean_kernel(const __half* __restrict__ xh, const int* __restrict__ rowStart,
                    const int* __restrict__ csr, float* __restrict__ m, int n) {
    const int lane = threadIdx.x & 63;
    const int g = lane >> 4;              // group 0..3
    const int gl = lane & 15;             // lane in group
    const int wave = threadIdx.x >> 6;
    const int gw = blockIdx.x * 4 + wave;
    const int nw = gridDim.x * 4;

    for (int node = gw; node < n; node += nw) {
        const int r0 = rowStart[node];
        const int r1 = rowStart[node + 1];
        float4 acc0 = make_float4(0.f, 0.f, 0.f, 0.f);
        float4 acc1 = make_float4(0.f, 0.f, 0.f, 0.f);

        int j = r0;
        for (; j + 16 <= r1; j += 16) {
            const int i0 = csr[j + 0  + g];
            const int i1 = csr[j + 4  + g];
            const int i2 = csr[j + 8  + g];
            const int i3 = csr[j + 12 + g];
            addh4(acc0, &xh[(size_t)i0 * D + gl * 4]);
            addh4(acc1, &xh[(size_t)i1 * D + gl * 4]);
            addh4(acc0, &xh[(size_t)i2 * D + gl * 4]);
            addh4(acc1, &xh[(size_t)i3 * D + gl * 4]);
        }
        const int rem = r1 - j;
        if (rem > 0) {
            if (0 + g < rem) {
                const int sidx = csr[j + 0 + g];
                addh4(acc0, &xh[(size_t)sidx * D + gl * 4]);
            }
            if (4 + g < rem) {
                const int sidx = csr[j + 4 + g];
                addh4(acc1, &xh[(size_t)sidx * D + gl * 4]);
            }
            if (8 + g < rem) {
                const int sidx = csr[j + 8 + g];
                addh4(acc0, &xh[(size_t)sidx * D + gl * 4]);
            }
            if (12 + g < rem) {
                const int sidx = csr[j + 12 + g];
                addh4(acc1, &xh[(size_t)sidx * D + gl * 4]);
            }
        }

        float4 a;
        a.x = acc0.x + acc1.x; a.y = acc0.y + acc1.y;
        a.z = acc0.z + acc1.z; a.w = acc0.w + acc1.w;
        a.x += __shfl_xor(a.x, 16); a.y += __shfl_xor(a.y, 16);
        a.z += __shfl_xor(a.z, 16); a.w += __shfl_xor(a.w, 16);
        a.x += __shfl_xor(a.x, 32); a.y += __shfl_xor(a.y, 32);
        a.z += __shfl_xor(a.z, 32); a.w += __shfl_xor(a.w, 32);

        if (lane < 16) {
            const float rdeg = 1.0f / fmaxf((float)(r1 - r0), 1.0f);
            float4 o = make_float4(a.x * rdeg, a.y * rdeg, a.z * rdeg, a.w * rdeg);
            *(float4*)&m[(size_t)node * D + gl * 4] = o;
        }
    }
}

// ---------------------------------------------------------------------------
// Fused SAGE transform: h = ELU(m@Wa + ba + x@Wb). Both weight columns
// register-resident (136 VGPR needed). KEY FIX vs rounds 3/6/7: LLVM's
// AMDGPU scheduler is occupancy-GREEDY -- launch_bounds' 2nd arg is only a
// MINIMUM waves/EU, and the scheduler remats/spills registers to push
// occupancy ABOVE it (measured: (256,3) -> 72 VGPR / 7 waves, weights
// reloaded every node, 54 us). amdgpu_waves_per_eu(2,3) sets max=3: >3
// waves is now illegal, so economizing below ~170 VGPR buys nothing and the
// allocator keeps the weight arrays resident. asm pins block remat on top.
// ---------------------------------------------------------------------------
__global__
__attribute__((amdgpu_flat_work_group_size(256, 256)))
__attribute__((amdgpu_waves_per_eu(2, 3)))
void fused_mm_kernel(const float* __restrict__ m,
                     const float* __restrict__ xres,
                     const float* __restrict__ Wa,
                     const float* __restrict__ ba,
                     const float* __restrict__ Wb,
                     float* __restrict__ out,
                     __half* __restrict__ hout,   // nullable
                     int n) {
    const int lane = threadIdx.x & 63;
    const int wave = threadIdx.x >> 6;
    const int gw = blockIdx.x * 4 + wave;
    const int nw = gridDim.x * 4;

    float wa[D], wb[D];
#pragma unroll
    for (int k = 0; k < D; ++k) wa[k] = Wa[k * D + lane];   // column `lane`
#pragma unroll
    for (int k = 0; k < D; ++k) wb[k] = Wb[k * D + lane];
#pragma unroll
    for (int k = 0; k < D; ++k) {
        asm volatile("" : "+v"(wa[k]));   // anti-remat: pin to VGPR
        asm volatile("" : "+v"(wb[k]));
    }
    const float bva = ba[lane];

    for (int node = gw; node < n; node += nw) {
        const unsigned mu = __float_as_uint(m[(size_t)node * D + lane]);
        const unsigned xu = __float_as_uint(xres[(size_t)node * D + lane]);
        float o0 = bva, o1 = 0.0f, o2 = 0.0f, o3 = 0.0f;
#pragma unroll
        for (int k = 0; k < D; k += 4) {
            const float sm0 = __uint_as_float(__builtin_amdgcn_readlane(mu, k + 0));
            const float sm1 = __uint_as_float(__builtin_amdgcn_readlane(mu, k + 1));
            const float sm2 = __uint_as_float(__builtin_amdgcn_readlane(mu, k + 2));
            const float sm3 = __uint_as_float(__builtin_amdgcn_readlane(mu, k + 3));
            const float sx0 = __uint_as_float(__builtin_amdgcn_readlane(xu, k + 0));
            const float sx1 = __uint_as_float(__builtin_amdgcn_readlane(xu, k + 1));
            const float sx2 = __uint_as_float(__builtin_amdgcn_readlane(xu, k + 2));
            const float sx3 = __uint_as_float(__builtin_amdgcn_readlane(xu, k + 3));
            o0 = fmaf(sm0, wa[k + 0], o0); o0 = fmaf(sx0, wb[k + 0], o0);
            o1 = fmaf(sm1, wa[k + 1], o1); o1 = fmaf(sx1, wb[k + 1], o1);
            o2 = fmaf(sm2, wa[k + 2], o2); o2 = fmaf(sx2, wb[k + 2], o2);
            o3 = fmaf(sm3, wa[k + 3], o3); o3 = fmaf(sx3, wb[k + 3], o3);
        }
        float h = (o0 + o1) + (o2 + o3);
        h = h > 0.0f ? h : expm1f(h);   // ELU(alpha=1)
        out[(size_t)node * D + lane] = h;
        if (hout) hout[(size_t)node * D + lane] = __float2half_rn(h);
    }
}

// ---------------------------------------------------------------------------
// Final linear: out = h@Wlin + blin. Single register-resident weight column
// (~80 VGPR -- fits the greedy allocator's targets fine, unchanged).
// ---------------------------------------------------------------------------
__global__ __launch_bounds__(256, 4)
void final_mm_kernel(const float* __restrict__ h,
                     const float* __restrict__ W,
                     const float* __restrict__ bias,
                     float* __restrict__ out,
                     int n) {
    const int lane = threadIdx.x & 63;
    const int wave = threadIdx.x >> 6;
    const int gw = blockIdx.x * 4 + wave;
    const int nw = gridDim.x * 4;

    float w[D];
#pragma unroll
    for (int k = 0; k < D; ++k) w[k] = W[k * D + lane];   // column `lane`
    const float bv = bias[lane];

    for (int node = gw; node < n; node += nw) {
        const unsigned hu = __float_as_uint(h[(size_t)node * D + lane]);
        float o0 = bv, o1 = 0.0f, o2 = 0.0f, o3 = 0.0f;
#pragma unroll
        for (int k = 0; k < D; k += 4) {
            o0 = fmaf(__uint_as_float(__builtin_amdgcn_readlane(hu, k + 0)), w[k + 0], o0);
            o1 = fmaf(__uint_as_float(__builtin_amdgcn_readlane(hu, k + 1)), w[k + 1], o1);
            o2 = fmaf(__uint_as_float(__builtin_amdgcn_readlane(hu, k + 2)), w[k + 2], o2);
            o3 = fmaf(__uint_as_float(__builtin_amdgcn_readlane(hu, k + 3)), w[k + 3], o3);
        }
        out[(size_t)node * D + lane] = (o0 + o1) + (o2 + o3);
    }
}

extern "C" void kernel_launch(void* const* d_in, const int* in_sizes, int n_in,
                              void* d_out, int out_size, void* d_ws, size_t ws_size,
                              hipStream_t stream) {
    const float* x    = (const float*)d_in[0];
    const int*   ei   = (const int*)d_in[1];
    const float* W1l  = (const float*)d_in[2];
    const float* b1   = (const float*)d_in[3];
    const float* W1r  = (const float*)d_in[4];
    const float* W2l  = (const float*)d_in[5];
    const float* b2   = (const float*)d_in[6];
    const float* W2r  = (const float*)d_in[7];
    const float* Wlin = (const float*)d_in[8];
    const float* blin = (const float*)d_in[9];

    const int N_ = in_sizes[0] / D;      // 100000
    const int E_ = in_sizes[1] / 2;      // 1600000
    const int* src = ei;
    const int* dst = ei + E_;

    // workspace layout
    int* bcnt     = (int*)d_ws;                     // MAXBUCK
    int* bbase    = bcnt + MAXBUCK;                 // MAXBUCK+1
    int* cursor   = bbase + MAXBUCK + 1;            // MAXBUCK
    int* rowStart = cursor + MAXBUCK;               // N+1
    unsigned* pairs = (unsigned*)(rowStart + N_ + 1);// E (packed src<<7|dloc)
    int* csr      = (int*)(pairs + E_);             // E
    size_t iofs = (size_t)((csr + E_) - (int*)d_ws);
    iofs = (iofs + 3) & ~(size_t)3;                 // 16B-align float region
    float* mbuf   = (float*)d_ws + iofs;            // N*64 (aggregated mean)
    float* hbuf   = mbuf + (size_t)N_ * D;          // N*64 (h1, then h2 in place)
    // fp16 feature buffer: x-half for layer 1, then h1-half for layer 2
    __half* fh    = (__half*)(hbuf + (size_t)N_ * D); // N*64 halves (12.8 MB)

    const int nbuck = (N_ + BNODES - 1) >> BSHIFT;          // 782
    const int npart = (E_ + PA_EDGES - 1) / PA_EDGES;       // 391

    hipMemsetAsync(bcnt, 0, (size_t)MAXBUCK * sizeof(int), stream);

    bhist_kernel<<<npart, 256, 0, stream>>>(dst, bcnt, E_, nbuck);
    bucket_scan_kernel<<<1, 256, 0, stream>>>(bcnt, bbase, cursor, nbuck, E_);
    partition_kernel<<<npart, 256, 0, stream>>>(src, dst, cursor, pairs, E_, nbuck);
    bucket_fill_kernel<<<nbuck, 256, 0, stream>>>(pairs, bbase, rowStart, csr, N_, E_);
    cast_half_kernel<<<1024, 256, 0, stream>>>(x, fh, N_ * D / 2);

    // Layer 1: m1 = mean(xh[nbrs]) ; h1 = ELU(m1@W1l + b1 + x@W1r)  (+h1 fp16)
    aggmean_kernel<<<2048, 256, 0, stream>>>(fh, rowStart, csr, mbuf, N_);
    fused_mm_kernel<<<2048, 256, 0, stream>>>(mbuf, x, W1l, b1, W1r, hbuf, fh, N_);
    // Layer 2: m2 = mean(h1h[nbrs]) ; h2 = ELU(m2@W2l + b2 + h1@W2r)  (in place)
    aggmean_kernel<<<2048, 256, 0, stream>>>(fh, rowStart, csr, mbuf, N_);
    fused_mm_kernel<<<2048, 256, 0, stream>>>(mbuf, hbuf, W2l, b2, W2r, hbuf, nullptr, N_);
    // Final: out = h2@Wlin + blin
    final_mm_kernel<<<2048, 256, 0, stream>>>(hbuf, Wlin, blin, (float*)d_out, N_);
}